// Round 4
// baseline (15165.237 us; speedup 1.0000x reference)
//
#include <hip/hip_runtime.h>
#include <hip/hip_bf16.h>

// GPT-2-ish forward, fp32 correctness-first baseline (resubmit; infra failures only).
// B=2 T=1024 D=1024 H=16 DH=64 L=8 DFF=4096 V=50257.
// Workspace overlay: mlp aliases qkvB/attn region -> peak ws 48 MB.

constexpr int Tn  = 1024;
constexpr int Dn  = 1024;
constexpr int Hn  = 16;
constexpr int DHn = 64;
constexpr int D3  = 3072;   // 3*D
constexpr int DFFn = 4096;
constexpr int Ln  = 8;
constexpr int Bn  = 2;
constexpr int Vn  = 50257;

#define DEV_INLINE __device__ __forceinline__

DEV_INLINE float gelu_exact(float v) {
    return 0.5f * v * (1.0f + erff(v * 0.70710678118654752f));
}

// ---------------- embedding: x = wte[idx] + wpe ----------------
__global__ __launch_bounds__(256) void embed_kernel(
    const int* __restrict__ idx, const float* __restrict__ wte,
    const float* __restrict__ wpe, float* __restrict__ x)
{
    const int n   = blockIdx.x;          // 0..2047
    const int t   = n & (Tn - 1);
    const int tok = idx[n];
    const int tid = threadIdx.x;         // 256 threads * float4 = 1024 floats
    float4 a = reinterpret_cast<const float4*>(wte + (size_t)tok * Dn)[tid];
    float4 p = reinterpret_cast<const float4*>(wpe + (size_t)t   * Dn)[tid];
    a.x += p.x; a.y += p.y; a.z += p.z; a.w += p.w;
    reinterpret_cast<float4*>(x + (size_t)n * Dn)[tid] = a;
}

// ---------------- layernorm (one block per row, D=1024) ----------------
__global__ __launch_bounds__(256) void ln_kernel(
    const float* __restrict__ x, const float* __restrict__ w,
    const float* __restrict__ b, float* __restrict__ y)
{
    const int n   = blockIdx.x;
    const int tid = threadIdx.x;
    float4 v = reinterpret_cast<const float4*>(x + (size_t)n * Dn)[tid];
    float s  = v.x + v.y + v.z + v.w;
    float ss = v.x*v.x + v.y*v.y + v.z*v.z + v.w*v.w;
    #pragma unroll
    for (int off = 32; off > 0; off >>= 1) {
        s  += __shfl_xor(s,  off);
        ss += __shfl_xor(ss, off);
    }
    __shared__ float red[8];
    const int wid = tid >> 6;
    if ((tid & 63) == 0) { red[wid*2] = s; red[wid*2+1] = ss; }
    __syncthreads();
    const float S  = red[0] + red[2] + red[4] + red[6];
    const float SS = red[1] + red[3] + red[5] + red[7];
    const float mean = S * (1.0f / Dn);
    const float var  = SS * (1.0f / Dn) - mean * mean;
    const float inv  = rsqrtf(var + 1e-5f);
    const float4 wv = reinterpret_cast<const float4*>(w)[tid];
    const float4 bv = reinterpret_cast<const float4*>(b)[tid];
    float4 o;
    o.x = (v.x - mean) * inv * wv.x + bv.x;
    o.y = (v.y - mean) * inv * wv.y + bv.y;
    o.z = (v.z - mean) * inv * wv.z + bv.z;
    o.w = (v.w - mean) * inv * wv.w + bv.w;
    reinterpret_cast<float4*>(y + (size_t)n * Dn)[tid] = o;
}

// ---------------- GEMM NN: C[N,M] = A[N,K] @ W[K,M] (+bias)(+res)(+gelu) ----
// 64x64 block tile, BK=16, 256 threads, 4x4 per thread.
__global__ __launch_bounds__(256) void gemm_nn(
    const float* __restrict__ A, const float* __restrict__ W,
    const float* __restrict__ bias, const float* __restrict__ res,
    float* __restrict__ C, int K, int M, int act)
{
    const int m0  = blockIdx.x * 64;
    const int n0  = blockIdx.y * 64;
    const int tid = threadIdx.x;

    __shared__ float As[64][17];                 // [n][k], pad to break conflicts
    alignas(16) __shared__ float Ws[16][68];     // [k][m], float4-readable

    const int ar = tid >> 4, ac = tid & 15;      // A load: row group / k
    const int wr = tid >> 6, wc = tid & 63;      // W load: k group / m
    const int tx = tid & 15, ty = tid >> 4;      // output 4x4 tile coords

    float acc[4][4] = {};

    for (int k0 = 0; k0 < K; k0 += 16) {
        #pragma unroll
        for (int i = 0; i < 4; ++i)
            As[ar + i*16][ac] = A[(size_t)(n0 + ar + i*16) * K + k0 + ac];
        #pragma unroll
        for (int i = 0; i < 4; ++i)
            Ws[wr + i*4][wc] = W[(size_t)(k0 + wr + i*4) * M + m0 + wc];
        __syncthreads();
        #pragma unroll
        for (int k = 0; k < 16; ++k) {
            const float a0 = As[tx*4+0][k];
            const float a1 = As[tx*4+1][k];
            const float a2 = As[tx*4+2][k];
            const float a3 = As[tx*4+3][k];
            const float4 bq = *reinterpret_cast<const float4*>(&Ws[k][ty*4]);
            acc[0][0] += a0*bq.x; acc[0][1] += a0*bq.y; acc[0][2] += a0*bq.z; acc[0][3] += a0*bq.w;
            acc[1][0] += a1*bq.x; acc[1][1] += a1*bq.y; acc[1][2] += a1*bq.z; acc[1][3] += a1*bq.w;
            acc[2][0] += a2*bq.x; acc[2][1] += a2*bq.y; acc[2][2] += a2*bq.z; acc[2][3] += a2*bq.w;
            acc[3][0] += a3*bq.x; acc[3][1] += a3*bq.y; acc[3][2] += a3*bq.z; acc[3][3] += a3*bq.w;
        }
        __syncthreads();
    }

    float4 bv = make_float4(0.f, 0.f, 0.f, 0.f);
    if (bias) bv = *reinterpret_cast<const float4*>(&bias[m0 + ty*4]);
    #pragma unroll
    for (int i = 0; i < 4; ++i) {
        const size_t row = (size_t)(n0 + tx*4 + i);
        float4 v = make_float4(acc[i][0] + bv.x, acc[i][1] + bv.y,
                               acc[i][2] + bv.z, acc[i][3] + bv.w);
        if (res) {
            const float4 r4 = *reinterpret_cast<const float4*>(&res[row * M + m0 + ty*4]);
            v.x += r4.x; v.y += r4.y; v.z += r4.z; v.w += r4.w;
        }
        if (act == 1) {
            v.x = gelu_exact(v.x); v.y = gelu_exact(v.y);
            v.z = gelu_exact(v.z); v.w = gelu_exact(v.w);
        }
        *reinterpret_cast<float4*>(&C[row * M + m0 + ty*4]) = v;
    }
}

// ---------------- GEMM NT: C[N,M] = A[N,K] @ Bt[M,K]^T (head) ----------------
__global__ __launch_bounds__(256) void gemm_nt(
    const float* __restrict__ A, const float* __restrict__ Bt,
    float* __restrict__ C, int K, int M)
{
    const int m0  = blockIdx.x * 64;
    const int n0  = blockIdx.y * 64;
    const int tid = threadIdx.x;

    __shared__ float As[64][17];
    alignas(16) __shared__ float Bs[16][68];     // [k][m]

    const int ar = tid >> 4, ac = tid & 15;
    const int bk = tid & 15, bm = tid >> 4;      // B load: k fast (coalesced on K)
    const int tx = tid & 15, ty = tid >> 4;

    float acc[4][4] = {};

    for (int k0 = 0; k0 < K; k0 += 16) {
        #pragma unroll
        for (int i = 0; i < 4; ++i)
            As[ar + i*16][ac] = A[(size_t)(n0 + ar + i*16) * K + k0 + ac];
        #pragma unroll
        for (int i = 0; i < 4; ++i) {
            const int m = bm + i*16;
            Bs[bk][m] = (m0 + m < M) ? Bt[(size_t)(m0 + m) * K + k0 + bk] : 0.f;
        }
        __syncthreads();
        #pragma unroll
        for (int k = 0; k < 16; ++k) {
            const float a0 = As[tx*4+0][k];
            const float a1 = As[tx*4+1][k];
            const float a2 = As[tx*4+2][k];
            const float a3 = As[tx*4+3][k];
            const float4 bq = *reinterpret_cast<const float4*>(&Bs[k][ty*4]);
            acc[0][0] += a0*bq.x; acc[0][1] += a0*bq.y; acc[0][2] += a0*bq.z; acc[0][3] += a0*bq.w;
            acc[1][0] += a1*bq.x; acc[1][1] += a1*bq.y; acc[1][2] += a1*bq.z; acc[1][3] += a1*bq.w;
            acc[2][0] += a2*bq.x; acc[2][1] += a2*bq.y; acc[2][2] += a2*bq.z; acc[2][3] += a2*bq.w;
            acc[3][0] += a3*bq.x; acc[3][1] += a3*bq.y; acc[3][2] += a3*bq.z; acc[3][3] += a3*bq.w;
        }
        __syncthreads();
    }

    #pragma unroll
    for (int i = 0; i < 4; ++i) {
        const size_t row = (size_t)(n0 + tx*4 + i);
        #pragma unroll
        for (int j = 0; j < 4; ++j) {
            const int m = m0 + ty*4 + j;
            if (m < M) C[row * M + m] = acc[i][j];
        }
    }
}

// ---------------- causal flash attention, fp32 ----------------
// grid: (T/32 q-tiles, B*H). block: 256 threads = 4 waves.
// wave w owns q-rows w*8..w*8+7; lane = k-column (scores) = head-dim col (PV out).
__global__ __launch_bounds__(256) void attn_kernel(
    const float* __restrict__ qkv, float* __restrict__ out)
{
    const int qt   = blockIdx.x;         // 0..31
    const int bh   = blockIdx.y;         // 0..31
    const int b    = bh >> 4;
    const int h    = bh & 15;
    const int tid  = threadIdx.x;
    const int lane = tid & 63;
    const int w    = tid >> 6;

    __shared__ float Qs[32][65];
    __shared__ float Ks[64][65];
    __shared__ float Vs[64][65];
    __shared__ float Ps[32][64];

    const float scale = 0.125f;          // 1/sqrt(64)

    // load Q tile (32x64), scaled
    #pragma unroll
    for (int i = 0; i < 2; ++i) {
        const int f = tid + i*256;
        const int r = f >> 4, c = (f & 15) * 4;
        const float4 q = *reinterpret_cast<const float4*>(
            qkv + (size_t)(b*Tn + qt*32 + r) * D3 + h*DHn + c);
        Qs[r][c+0] = q.x * scale; Qs[r][c+1] = q.y * scale;
        Qs[r][c+2] = q.z * scale; Qs[r][c+3] = q.w * scale;
    }

    float m_i[8], l_i[8], o_i[8];
    #pragma unroll
    for (int i = 0; i < 8; ++i) { m_i[i] = -1e30f; l_i[i] = 0.f; o_i[i] = 0.f; }

    const int ktmax = (qt*32 + 31) >> 6;
    for (int kt = 0; kt <= ktmax; ++kt) {
        __syncthreads();   // previous tile's LDS fully consumed; Qs visible (1st iter)
        #pragma unroll
        for (int i = 0; i < 4; ++i) {
            const int f = tid + i*256;
            const int r = f >> 4, c = (f & 15) * 4;
            const size_t base = (size_t)(b*Tn + kt*64 + r) * D3 + h*DHn + c;
            const float4 kq = *reinterpret_cast<const float4*>(qkv + base + Dn);
            const float4 vq = *reinterpret_cast<const float4*>(qkv + base + 2*Dn);
            Ks[r][c+0]=kq.x; Ks[r][c+1]=kq.y; Ks[r][c+2]=kq.z; Ks[r][c+3]=kq.w;
            Vs[r][c+0]=vq.x; Vs[r][c+1]=vq.y; Vs[r][c+2]=vq.z; Vs[r][c+3]=vq.w;
        }
        __syncthreads();

        // scores for this wave's 8 rows; lane = k-col within tile
        float s[8];
        #pragma unroll
        for (int i = 0; i < 8; ++i) s[i] = 0.f;
        for (int d = 0; d < 64; ++d) {
            const float kv = Ks[lane][d];
            #pragma unroll
            for (int i = 0; i < 8; ++i) s[i] += Qs[w*8+i][d] * kv;
        }
        const int kg = kt*64 + lane;
        #pragma unroll
        for (int i = 0; i < 8; ++i) {
            const int qg = qt*32 + w*8 + i;
            if (kg > qg) s[i] = -1e30f;
        }

        // online softmax per row (64-lane butterfly reduce)
        #pragma unroll
        for (int i = 0; i < 8; ++i) {
            float tmax = s[i];
            #pragma unroll
            for (int off = 32; off > 0; off >>= 1)
                tmax = fmaxf(tmax, __shfl_xor(tmax, off));
            const float mn   = fmaxf(m_i[i], tmax);
            const float p    = expf(s[i] - mn);
            const float corr = expf(m_i[i] - mn);
            float psum = p;
            #pragma unroll
            for (int off = 32; off > 0; off >>= 1)
                psum += __shfl_xor(psum, off);
            l_i[i] = l_i[i] * corr + psum;
            m_i[i] = mn;
            o_i[i] *= corr;
            Ps[w*8+i][lane] = p;
        }
        __syncthreads();   // order Ps/Vs use vs next-tile overwrite

        // PV: lane = output head-dim column
        for (int kc = 0; kc < 64; ++kc) {
            const float vv = Vs[kc][lane];
            #pragma unroll
            for (int i = 0; i < 8; ++i) o_i[i] += Ps[w*8+i][kc] * vv;
        }
    }

    #pragma unroll
    for (int i = 0; i < 8; ++i) {
        const int r = qt*32 + w*8 + i;
        out[(size_t)(b*Tn + r) * Dn + h*DHn + lane] = o_i[i] / l_i[i];
    }
}

// ---------------- launch ----------------
extern "C" void kernel_launch(void* const* d_in, const int* in_sizes, int n_in,
                              void* d_out, int out_size, void* d_ws, size_t ws_size,
                              hipStream_t stream) {
    (void)in_sizes; (void)n_in; (void)out_size; (void)ws_size;

    const int* idx     = (const int*)  d_in[0];
    const float* wte   = (const float*)d_in[1];
    const float* wpe   = (const float*)d_in[2];
    const float* ln1w  = (const float*)d_in[3];
    const float* ln1b  = (const float*)d_in[4];
    const float* qkvw  = (const float*)d_in[5];
    const float* qkvb  = (const float*)d_in[6];
    const float* outw  = (const float*)d_in[7];
    const float* outb  = (const float*)d_in[8];
    const float* ln2w  = (const float*)d_in[9];
    const float* ln2b  = (const float*)d_in[10];
    const float* fc1w  = (const float*)d_in[11];
    const float* fc1b  = (const float*)d_in[12];
    const float* fc2w  = (const float*)d_in[13];
    const float* fc2b  = (const float*)d_in[14];
    const float* lnfw  = (const float*)d_in[15];
    const float* lnfb  = (const float*)d_in[16];
    const float* headw = (const float*)d_in[17];

    const int N = Bn * Tn;   // 2048 token rows

    // workspace layout (fp32), peak 48 MB:
    //   x    [N,D]   8 MB
    //   hbuf [N,D]   8 MB
    //   qkvB [N,3D] 24 MB  } mlp [N,DFF] 32 MB overlays qkvB+attn
    //   attn [N,D]   8 MB  } (qkvB dead after attn_kernel, attn dead after out-proj)
    float* x    = (float*)d_ws;
    float* hbuf = x    + (size_t)N * Dn;
    float* qkvB = hbuf + (size_t)N * Dn;
    float* attn = qkvB + (size_t)N * D3;
    float* mlp  = qkvB;                        // overlay: [N, DFF] = qkvB(24MB)+attn(8MB)
    float* logits = (float*)d_out;

    embed_kernel<<<N, 256, 0, stream>>>(idx, wte, wpe, x);

    for (int l = 0; l < Ln; ++l) {
        ln_kernel<<<N, 256, 0, stream>>>(x, ln1w + (size_t)l*Dn, ln1b + (size_t)l*Dn, hbuf);
        gemm_nn<<<dim3(D3/64, N/64), 256, 0, stream>>>(
            hbuf, qkvw + (size_t)l*Dn*D3, qkvb + (size_t)l*D3, nullptr, qkvB, Dn, D3, 0);
        attn_kernel<<<dim3(Tn/32, Bn*Hn), 256, 0, stream>>>(qkvB, attn);
        gemm_nn<<<dim3(Dn/64, N/64), 256, 0, stream>>>(
            attn, outw + (size_t)l*Dn*Dn, outb + (size_t)l*Dn, x, x, Dn, Dn, 0);
        ln_kernel<<<N, 256, 0, stream>>>(x, ln2w + (size_t)l*Dn, ln2b + (size_t)l*Dn, hbuf);
        gemm_nn<<<dim3(DFFn/64, N/64), 256, 0, stream>>>(
            hbuf, fc1w + (size_t)l*Dn*DFFn, fc1b + (size_t)l*DFFn, nullptr, mlp, Dn, DFFn, 1);
        gemm_nn<<<dim3(Dn/64, N/64), 256, 0, stream>>>(
            mlp, fc2w + (size_t)l*DFFn*Dn, fc2b + (size_t)l*Dn, x, x, DFFn, Dn, 0);
    }

    ln_kernel<<<N, 256, 0, stream>>>(x, lnfw, lnfb, hbuf);
    gemm_nt<<<dim3((Vn + 63)/64, N/64), 256, 0, stream>>>(hbuf, headw, logits, Dn, Vn);
}

// Round 12
// 5114.919 us; speedup vs baseline: 2.9649x; 2.9649x over previous
//
#include <hip/hip_runtime.h>
#include <hip/hip_bf16.h>

// GPT-2-ish forward. bf16-MFMA GEMMs (fp32 accumulate), fp32 attention/LN/residual.
// B=2 T=1024 D=1024 H=16 DH=64 L=8 DFF=4096 V=50257.
// Falls back to validated fp32 path if ws_size < ~332 MB.
// (Resubmit: rounds 4-10 died on GPU acquisition; bf16 path has never executed.)

constexpr int Tn  = 1024;
constexpr int Dn  = 1024;
constexpr int Hn  = 16;
constexpr int DHn = 64;
constexpr int D3  = 3072;   // 3*D
constexpr int DFFn = 4096;
constexpr int Ln  = 8;
constexpr int Bn  = 2;
constexpr int Vn  = 50257;

#define DEV_INLINE __device__ __forceinline__

typedef __bf16 bf16x8 __attribute__((ext_vector_type(8)));
typedef __bf16 bf16x4 __attribute__((ext_vector_type(4)));
typedef float  f32x4  __attribute__((ext_vector_type(4)));

DEV_INLINE float gelu_exact(float v) {
    return 0.5f * v * (1.0f + erff(v * 0.70710678118654752f));
}

// global -> LDS async 16B copy (linear LDS dest = wave-uniform base + lane*16)
typedef const __attribute__((address_space(1))) void* gas_ptr;
typedef __attribute__((address_space(3))) void*       las_ptr;
DEV_INLINE void g2lds16(const void* g, void* l) {
    __builtin_amdgcn_global_load_lds((gas_ptr)g, (las_ptr)l, 16, 0, 0);
}

// ---------------- embedding: x = wte[idx] + wpe ----------------
__global__ __launch_bounds__(256) void embed_kernel(
    const int* __restrict__ idx, const float* __restrict__ wte,
    const float* __restrict__ wpe, float* __restrict__ x)
{
    const int n   = blockIdx.x;
    const int t   = n & (Tn - 1);
    const int tok = idx[n];
    const int tid = threadIdx.x;
    float4 a = reinterpret_cast<const float4*>(wte + (size_t)tok * Dn)[tid];
    float4 p = reinterpret_cast<const float4*>(wpe + (size_t)t   * Dn)[tid];
    a.x += p.x; a.y += p.y; a.z += p.z; a.w += p.w;
    reinterpret_cast<float4*>(x + (size_t)n * Dn)[tid] = a;
}

// ---------------- layernorm fp32 -> fp32 ----------------
__global__ __launch_bounds__(256) void ln_kernel(
    const float* __restrict__ x, const float* __restrict__ w,
    const float* __restrict__ b, float* __restrict__ y)
{
    const int n   = blockIdx.x;
    const int tid = threadIdx.x;
    float4 v = reinterpret_cast<const float4*>(x + (size_t)n * Dn)[tid];
    float s  = v.x + v.y + v.z + v.w;
    float ss = v.x*v.x + v.y*v.y + v.z*v.z + v.w*v.w;
    #pragma unroll
    for (int off = 32; off > 0; off >>= 1) {
        s  += __shfl_xor(s,  off);
        ss += __shfl_xor(ss, off);
    }
    __shared__ float red[8];
    const int wid = tid >> 6;
    if ((tid & 63) == 0) { red[wid*2] = s; red[wid*2+1] = ss; }
    __syncthreads();
    const float S  = red[0] + red[2] + red[4] + red[6];
    const float SS = red[1] + red[3] + red[5] + red[7];
    const float mean = S * (1.0f / Dn);
    const float var  = SS * (1.0f / Dn) - mean * mean;
    const float inv  = rsqrtf(var + 1e-5f);
    const float4 wv = reinterpret_cast<const float4*>(w)[tid];
    const float4 bv = reinterpret_cast<const float4*>(b)[tid];
    float4 o;
    o.x = (v.x - mean) * inv * wv.x + bv.x;
    o.y = (v.y - mean) * inv * wv.y + bv.y;
    o.z = (v.z - mean) * inv * wv.z + bv.z;
    o.w = (v.w - mean) * inv * wv.w + bv.w;
    reinterpret_cast<float4*>(y + (size_t)n * Dn)[tid] = o;
}

// ---------------- layernorm fp32 -> bf16 ----------------
__global__ __launch_bounds__(256) void ln_bf16_kernel(
    const float* __restrict__ x, const float* __restrict__ w,
    const float* __restrict__ b, __bf16* __restrict__ y)
{
    const int n   = blockIdx.x;
    const int tid = threadIdx.x;
    float4 v = reinterpret_cast<const float4*>(x + (size_t)n * Dn)[tid];
    float s  = v.x + v.y + v.z + v.w;
    float ss = v.x*v.x + v.y*v.y + v.z*v.z + v.w*v.w;
    #pragma unroll
    for (int off = 32; off > 0; off >>= 1) {
        s  += __shfl_xor(s,  off);
        ss += __shfl_xor(ss, off);
    }
    __shared__ float red[8];
    const int wid = tid >> 6;
    if ((tid & 63) == 0) { red[wid*2] = s; red[wid*2+1] = ss; }
    __syncthreads();
    const float S  = red[0] + red[2] + red[4] + red[6];
    const float SS = red[1] + red[3] + red[5] + red[7];
    const float mean = S * (1.0f / Dn);
    const float var  = SS * (1.0f / Dn) - mean * mean;
    const float inv  = rsqrtf(var + 1e-5f);
    const float4 wv = reinterpret_cast<const float4*>(w)[tid];
    const float4 bv = reinterpret_cast<const float4*>(b)[tid];
    bf16x4 o;
    o[0] = (__bf16)((v.x - mean) * inv * wv.x + bv.x);
    o[1] = (__bf16)((v.y - mean) * inv * wv.y + bv.y);
    o[2] = (__bf16)((v.z - mean) * inv * wv.z + bv.z);
    o[3] = (__bf16)((v.w - mean) * inv * wv.w + bv.w);
    reinterpret_cast<bf16x4*>(y + (size_t)n * Dn)[tid] = o;
}

// ---------------- weight prep: W[K,M] fp32 -> Wt[M,K] bf16 (per layer z) ----
__global__ __launch_bounds__(256) void transpose_bf16_kernel(
    const float* __restrict__ W, __bf16* __restrict__ Wt, int K, int M)
{
    const int l  = blockIdx.z;
    const int k0 = blockIdx.y * 32, m0 = blockIdx.x * 32;
    __shared__ float t[32][33];
    const int tid = threadIdx.x;
    const int r = tid >> 3, c4 = (tid & 7) * 4;
    const float4 v = *reinterpret_cast<const float4*>(
        W + ((size_t)l * K + k0 + r) * M + m0 + c4);
    t[r][c4+0] = v.x; t[r][c4+1] = v.y; t[r][c4+2] = v.z; t[r][c4+3] = v.w;
    __syncthreads();
    bf16x4 o;
    o[0] = (__bf16)t[c4+0][r]; o[1] = (__bf16)t[c4+1][r];
    o[2] = (__bf16)t[c4+2][r]; o[3] = (__bf16)t[c4+3][r];
    *reinterpret_cast<bf16x4*>(Wt + ((size_t)l * M + m0 + r) * K + k0 + c4) = o;
}

// ---------------- fp32 -> bf16 elementwise (head weight) ----------------
__global__ __launch_bounds__(256) void cvt_bf16_kernel(
    const float* __restrict__ in, __bf16* __restrict__ out)
{
    const int i = blockIdx.x * 256 + threadIdx.x;
    float4 v = reinterpret_cast<const float4*>(in)[i];
    bf16x4 o;
    o[0] = (__bf16)v.x; o[1] = (__bf16)v.y; o[2] = (__bf16)v.z; o[3] = (__bf16)v.w;
    reinterpret_cast<bf16x4*>(out)[i] = o;
}

// ---------------- bf16 MFMA GEMM: C[N,M] = A[N,K] @ Bt[M,K]^T ----------------
// EPI: 0 = +bias -> fp32 | 1 = +bias,gelu -> bf16 | 2 = +bias+res -> fp32
//      3 = plain -> fp32, M bounds-checked (head; Bt must have >=94KB pad after)
// 256 threads = 4 waves (2x2); wave tile (BM/2)x(BN/2); mfma 16x16x32, BK=32.
template <int BM, int BN, int EPI>
__global__ __launch_bounds__(256) void gemm_bf16(
    const __bf16* __restrict__ A, const __bf16* __restrict__ Bt,
    const float* __restrict__ bias, const float* res,
    void* Cout, int K, int M)
{
    constexpr int BK = 32;
    constexpr int FM = BM / 32, FN = BN / 32;   // 16x16 frags per wave
    __shared__ __bf16 As[BM * BK];
    __shared__ __bf16 Bs[BN * BK];

    const int tid  = threadIdx.x;
    const int lane = tid & 63, wid = tid >> 6;
    const int wr = wid >> 1, wc = wid & 1;
    const int n0 = blockIdx.y * BM, m0 = blockIdx.x * BN;

    f32x4 acc[FM][FN] = {};

    // staging geometry: per 4KB issue, tid covers row=(i*64 + tid/4), kcol=(tid%4)*8
    const int rs = tid >> 2;
    const int kc = (tid & 3) * 8;
    const __bf16* Ab = A  + (size_t)n0 * K + kc;
    const __bf16* Bb = Bt + (size_t)m0 * K + kc;

    for (int k0 = 0; k0 < K; k0 += BK) {
        #pragma unroll
        for (int i = 0; i < (BM * BK) / 2048; ++i)
            g2lds16(Ab + (size_t)(i * 64 + rs) * K + k0,
                    (char*)As + i * 4096 + tid * 16);
        #pragma unroll
        for (int i = 0; i < (BN * BK) / 2048; ++i)
            g2lds16(Bb + (size_t)(i * 64 + rs) * K + k0,
                    (char*)Bs + i * 4096 + tid * 16);
        __syncthreads();   // drains vmcnt -> staged data visible

        const int ko = (lane >> 4) * 8;
        bf16x8 af[FM], bf[FN];
        #pragma unroll
        for (int mi = 0; mi < FM; ++mi)
            af[mi] = *reinterpret_cast<const bf16x8*>(
                &As[(wr * (BM/2) + mi * 16 + (lane & 15)) * BK + ko]);
        #pragma unroll
        for (int ni = 0; ni < FN; ++ni)
            bf[ni] = *reinterpret_cast<const bf16x8*>(
                &Bs[(wc * (BN/2) + ni * 16 + (lane & 15)) * BK + ko]);
        #pragma unroll
        for (int mi = 0; mi < FM; ++mi)
            #pragma unroll
            for (int ni = 0; ni < FN; ++ni)
                acc[mi][ni] = __builtin_amdgcn_mfma_f32_16x16x32_bf16(
                    af[mi], bf[ni], acc[mi][ni], 0, 0, 0);
        __syncthreads();   // all waves done before next stage overwrites
    }

    // epilogue: C/D mapping col=lane&15, row=(lane>>4)*4+reg  [m89-verified]
    const int cl = lane & 15, rg = lane >> 4;
    const int row0 = n0 + wr * (BM/2);
    const int col0 = m0 + wc * (BN/2);
    #pragma unroll
    for (int mi = 0; mi < FM; ++mi) {
        #pragma unroll
        for (int ni = 0; ni < FN; ++ni) {
            const int col = col0 + ni * 16 + cl;
            if (EPI == 3 && col >= M) continue;
            const float bv = (EPI == 3) ? 0.0f : bias[col];
            #pragma unroll
            for (int r = 0; r < 4; ++r) {
                const int row = row0 + mi * 16 + rg * 4 + r;
                float v = acc[mi][ni][r] + bv;
                if (EPI == 2) v += res[(size_t)row * M + col];
                if (EPI == 1) {
                    ((__bf16*)Cout)[(size_t)row * M + col] = (__bf16)gelu_exact(v);
                } else {
                    ((float*)Cout)[(size_t)row * M + col] = v;
                }
            }
        }
    }
}

// ---------------- fp32 GEMM NN (fallback path) ----------------
__global__ __launch_bounds__(256) void gemm_nn(
    const float* __restrict__ A, const float* __restrict__ W,
    const float* __restrict__ bias, const float* res,
    float* C, int K, int M, int act)
{
    const int m0  = blockIdx.x * 64;
    const int n0  = blockIdx.y * 64;
    const int tid = threadIdx.x;

    __shared__ float As[64][17];
    alignas(16) __shared__ float Ws[16][68];

    const int ar = tid >> 4, ac = tid & 15;
    const int wr = tid >> 6, wc = tid & 63;
    const int tx = tid & 15, ty = tid >> 4;

    float acc[4][4] = {};

    for (int k0 = 0; k0 < K; k0 += 16) {
        #pragma unroll
        for (int i = 0; i < 4; ++i)
            As[ar + i*16][ac] = A[(size_t)(n0 + ar + i*16) * K + k0 + ac];
        #pragma unroll
        for (int i = 0; i < 4; ++i)
            Ws[wr + i*4][wc] = W[(size_t)(k0 + wr + i*4) * M + m0 + wc];
        __syncthreads();
        #pragma unroll
        for (int k = 0; k < 16; ++k) {
            const float a0 = As[tx*4+0][k];
            const float a1 = As[tx*4+1][k];
            const float a2 = As[tx*4+2][k];
            const float a3 = As[tx*4+3][k];
            const float4 bq = *reinterpret_cast<const float4*>(&Ws[k][ty*4]);
            acc[0][0] += a0*bq.x; acc[0][1] += a0*bq.y; acc[0][2] += a0*bq.z; acc[0][3] += a0*bq.w;
            acc[1][0] += a1*bq.x; acc[1][1] += a1*bq.y; acc[1][2] += a1*bq.z; acc[1][3] += a1*bq.w;
            acc[2][0] += a2*bq.x; acc[2][1] += a2*bq.y; acc[2][2] += a2*bq.z; acc[2][3] += a2*bq.w;
            acc[3][0] += a3*bq.x; acc[3][1] += a3*bq.y; acc[3][2] += a3*bq.z; acc[3][3] += a3*bq.w;
        }
        __syncthreads();
    }

    float4 bv = make_float4(0.f, 0.f, 0.f, 0.f);
    if (bias) bv = *reinterpret_cast<const float4*>(&bias[m0 + ty*4]);
    #pragma unroll
    for (int i = 0; i < 4; ++i) {
        const size_t row = (size_t)(n0 + tx*4 + i);
        float4 v = make_float4(acc[i][0] + bv.x, acc[i][1] + bv.y,
                               acc[i][2] + bv.z, acc[i][3] + bv.w);
        if (res) {
            const float4 r4 = *reinterpret_cast<const float4*>(&res[row * M + m0 + ty*4]);
            v.x += r4.x; v.y += r4.y; v.z += r4.z; v.w += r4.w;
        }
        if (act == 1) {
            v.x = gelu_exact(v.x); v.y = gelu_exact(v.y);
            v.z = gelu_exact(v.z); v.w = gelu_exact(v.w);
        }
        *reinterpret_cast<float4*>(&C[row * M + m0 + ty*4]) = v;
    }
}

// ---------------- fp32 GEMM NT (fallback head) ----------------
__global__ __launch_bounds__(256) void gemm_nt(
    const float* __restrict__ A, const float* __restrict__ Bt,
    float* __restrict__ C, int K, int M)
{
    const int m0  = blockIdx.x * 64;
    const int n0  = blockIdx.y * 64;
    const int tid = threadIdx.x;

    __shared__ float As[64][17];
    alignas(16) __shared__ float Bs[16][68];

    const int ar = tid >> 4, ac = tid & 15;
    const int bk = tid & 15, bm = tid >> 4;
    const int tx = tid & 15, ty = tid >> 4;

    float acc[4][4] = {};

    for (int k0 = 0; k0 < K; k0 += 16) {
        #pragma unroll
        for (int i = 0; i < 4; ++i)
            As[ar + i*16][ac] = A[(size_t)(n0 + ar + i*16) * K + k0 + ac];
        #pragma unroll
        for (int i = 0; i < 4; ++i) {
            const int m = bm + i*16;
            Bs[bk][m] = (m0 + m < M) ? Bt[(size_t)(m0 + m) * K + k0 + bk] : 0.f;
        }
        __syncthreads();
        #pragma unroll
        for (int k = 0; k < 16; ++k) {
            const float a0 = As[tx*4+0][k];
            const float a1 = As[tx*4+1][k];
            const float a2 = As[tx*4+2][k];
            const float a3 = As[tx*4+3][k];
            const float4 bq = *reinterpret_cast<const float4*>(&Bs[k][ty*4]);
            acc[0][0] += a0*bq.x; acc[0][1] += a0*bq.y; acc[0][2] += a0*bq.z; acc[0][3] += a0*bq.w;
            acc[1][0] += a1*bq.x; acc[1][1] += a1*bq.y; acc[1][2] += a1*bq.z; acc[1][3] += a1*bq.w;
            acc[2][0] += a2*bq.x; acc[2][1] += a2*bq.y; acc[2][2] += a2*bq.z; acc[2][3] += a2*bq.w;
            acc[3][0] += a3*bq.x; acc[3][1] += a3*bq.y; acc[3][2] += a3*bq.z; acc[3][3] += a3*bq.w;
        }
        __syncthreads();
    }

    #pragma unroll
    for (int i = 0; i < 4; ++i) {
        const size_t row = (size_t)(n0 + tx*4 + i);
        #pragma unroll
        for (int j = 0; j < 4; ++j) {
            const int m = m0 + ty*4 + j;
            if (m < M) C[row * M + m] = acc[i][j];
        }
    }
}

// ---------------- causal flash attention, fp32 compute, templated output ----
template <typename OT>
__global__ __launch_bounds__(256) void attn_kernel(
    const float* __restrict__ qkv, OT* __restrict__ out)
{
    const int qt   = blockIdx.x;
    const int bh   = blockIdx.y;
    const int b    = bh >> 4;
    const int h    = bh & 15;
    const int tid  = threadIdx.x;
    const int lane = tid & 63;
    const int w    = tid >> 6;

    __shared__ float Qs[32][65];
    __shared__ float Ks[64][65];
    __shared__ float Vs[64][65];
    __shared__ float Ps[32][64];

    const float scale = 0.125f;

    #pragma unroll
    for (int i = 0; i < 2; ++i) {
        const int f = tid + i*256;
        const int r = f >> 4, c = (f & 15) * 4;
        const float4 q = *reinterpret_cast<const float4*>(
            qkv + (size_t)(b*Tn + qt*32 + r) * D3 + h*DHn + c);
        Qs[r][c+0] = q.x * scale; Qs[r][c+1] = q.y * scale;
        Qs[r][c+2] = q.z * scale; Qs[r][c+3] = q.w * scale;
    }

    float m_i[8], l_i[8], o_i[8];
    #pragma unroll
    for (int i = 0; i < 8; ++i) { m_i[i] = -1e30f; l_i[i] = 0.f; o_i[i] = 0.f; }

    const int ktmax = (qt*32 + 31) >> 6;
    for (int kt = 0; kt <= ktmax; ++kt) {
        __syncthreads();
        #pragma unroll
        for (int i = 0; i < 4; ++i) {
            const int f = tid + i*256;
            const int r = f >> 4, c = (f & 15) * 4;
            const size_t base = (size_t)(b*Tn + kt*64 + r) * D3 + h*DHn + c;
            const float4 kq = *reinterpret_cast<const float4*>(qkv + base + Dn);
            const float4 vq = *reinterpret_cast<const float4*>(qkv + base + 2*Dn);
            Ks[r][c+0]=kq.x; Ks[r][c+1]=kq.y; Ks[r][c+2]=kq.z; Ks[r][c+3]=kq.w;
            Vs[r][c+0]=vq.x; Vs[r][c+1]=vq.y; Vs[r][c+2]=vq.z; Vs[r][c+3]=vq.w;
        }
        __syncthreads();

        float s[8];
        #pragma unroll
        for (int i = 0; i < 8; ++i) s[i] = 0.f;
        for (int d = 0; d < 64; ++d) {
            const float kv = Ks[lane][d];
            #pragma unroll
            for (int i = 0; i < 8; ++i) s[i] += Qs[w*8+i][d] * kv;
        }
        const int kg = kt*64 + lane;
        #pragma unroll
        for (int i = 0; i < 8; ++i) {
            const int qg = qt*32 + w*8 + i;
            if (kg > qg) s[i] = -1e30f;
        }

        #pragma unroll
        for (int i = 0; i < 8; ++i) {
            float tmax = s[i];
            #pragma unroll
            for (int off = 32; off > 0; off >>= 1)
                tmax = fmaxf(tmax, __shfl_xor(tmax, off));
            const float mn   = fmaxf(m_i[i], tmax);
            const float p    = expf(s[i] - mn);
            const float corr = expf(m_i[i] - mn);
            float psum = p;
            #pragma unroll
            for (int off = 32; off > 0; off >>= 1)
                psum += __shfl_xor(psum, off);
            l_i[i] = l_i[i] * corr + psum;
            m_i[i] = mn;
            o_i[i] *= corr;
            Ps[w*8+i][lane] = p;
        }
        __syncthreads();

        for (int kc = 0; kc < 64; ++kc) {
            const float vv = Vs[kc][lane];
            #pragma unroll
            for (int i = 0; i < 8; ++i) o_i[i] += Ps[w*8+i][kc] * vv;
        }
    }

    #pragma unroll
    for (int i = 0; i < 8; ++i) {
        const int r = qt*32 + w*8 + i;
        out[(size_t)(b*Tn + r) * Dn + h*DHn + lane] = (OT)(o_i[i] / l_i[i]);
    }
}

// ---------------- launch ----------------
extern "C" void kernel_launch(void* const* d_in, const int* in_sizes, int n_in,
                              void* d_out, int out_size, void* d_ws, size_t ws_size,
                              hipStream_t stream) {
    (void)in_sizes; (void)n_in; (void)out_size;

    const int* idx     = (const int*)  d_in[0];
    const float* wte   = (const float*)d_in[1];
    const float* wpe   = (const float*)d_in[2];
    const float* ln1w  = (const float*)d_in[3];
    const float* ln1b  = (const float*)d_in[4];
    const float* qkvw  = (const float*)d_in[5];
    const float* qkvb  = (const float*)d_in[6];
    const float* outw  = (const float*)d_in[7];
    const float* outb  = (const float*)d_in[8];
    const float* ln2w  = (const float*)d_in[9];
    const float* ln2b  = (const float*)d_in[10];
    const float* fc1w  = (const float*)d_in[11];
    const float* fc1b  = (const float*)d_in[12];
    const float* fc2w  = (const float*)d_in[13];
    const float* fc2b  = (const float*)d_in[14];
    const float* lnfw  = (const float*)d_in[15];
    const float* lnfb  = (const float*)d_in[16];
    const float* headw = (const float*)d_in[17];

    const int N = Bn * Tn;   // 2048
    float* logits = (float*)d_out;

    // ---- bf16-path workspace layout (bytes) ----
    char* p = (char*)d_ws;
    size_t off = 0;
    auto take = [&](size_t bytes) { char* r = p + off; off += bytes; return r; };
    float*  x      = (float*) take((size_t)N * Dn * 4);
    __bf16* hbufb  = (__bf16*)take((size_t)N * Dn * 2);
    float*  qkvB   = (float*) take((size_t)N * D3 * 4);      // mlpb aliases this
    __bf16* attnb  = (__bf16*)take((size_t)N * Dn * 2);
    __bf16* qkvw_t = (__bf16*)take((size_t)Ln * Dn * D3 * 2);
    __bf16* outw_t = (__bf16*)take((size_t)Ln * Dn * Dn * 2);
    __bf16* fc1w_t = (__bf16*)take((size_t)Ln * Dn * DFFn * 2);
    __bf16* fc2w_t = (__bf16*)take((size_t)Ln * DFFn * Dn * 2);
    __bf16* headb  = (__bf16*)take((size_t)Vn * Dn * 2);
    off += 1 << 20;                                          // pad for head OOB staging
    __bf16* mlpb   = (__bf16*)qkvB;                          // overlay (disjoint liveness)

    if (ws_size >= off) {
        // ================= bf16 MFMA path =================
        embed_kernel<<<N, 256, 0, stream>>>(idx, wte, wpe, x);

        transpose_bf16_kernel<<<dim3(D3/32,  Dn/32,  Ln), 256, 0, stream>>>(qkvw, qkvw_t, Dn, D3);
        transpose_bf16_kernel<<<dim3(Dn/32,  Dn/32,  Ln), 256, 0, stream>>>(outw, outw_t, Dn, Dn);
        transpose_bf16_kernel<<<dim3(DFFn/32, Dn/32, Ln), 256, 0, stream>>>(fc1w, fc1w_t, Dn, DFFn);
        transpose_bf16_kernel<<<dim3(Dn/32, DFFn/32, Ln), 256, 0, stream>>>(fc2w, fc2w_t, DFFn, Dn);
        cvt_bf16_kernel<<<Vn, 256, 0, stream>>>(headw, headb);   // V*D/4 = 256*Vn exactly

        for (int l = 0; l < Ln; ++l) {
            ln_bf16_kernel<<<N, 256, 0, stream>>>(x, ln1w + (size_t)l*Dn, ln1b + (size_t)l*Dn, hbufb);
            gemm_bf16<128,128,0><<<dim3(D3/128, N/128), 256, 0, stream>>>(
                hbufb, qkvw_t + (size_t)l*Dn*D3, qkvb + (size_t)l*D3, nullptr, qkvB, Dn, D3);
            attn_kernel<__bf16><<<dim3(Tn/32, Bn*Hn), 256, 0, stream>>>(qkvB, attnb);
            gemm_bf16<64,64,2><<<dim3(Dn/64, N/64), 256, 0, stream>>>(
                attnb, outw_t + (size_t)l*Dn*Dn, outb + (size_t)l*Dn, x, x, Dn, Dn);
            ln_bf16_kernel<<<N, 256, 0, stream>>>(x, ln2w + (size_t)l*Dn, ln2b + (size_t)l*Dn, hbufb);
            gemm_bf16<128,128,1><<<dim3(DFFn/128, N/128), 256, 0, stream>>>(
                hbufb, fc1w_t + (size_t)l*Dn*DFFn, fc1b + (size_t)l*DFFn, nullptr, mlpb, Dn, DFFn);
            gemm_bf16<64,64,2><<<dim3(Dn/64, N/64), 256, 0, stream>>>(
                mlpb, fc2w_t + (size_t)l*DFFn*Dn, fc2b + (size_t)l*Dn, x, x, DFFn, Dn);
        }

        ln_bf16_kernel<<<N, 256, 0, stream>>>(x, lnfw, lnfb, hbufb);
        gemm_bf16<128,128,3><<<dim3((Vn + 127)/128, N/128), 256, 0, stream>>>(
            hbufb, headb, nullptr, nullptr, logits, Dn, Vn);
    } else {
        // ================= fp32 fallback (validated baseline) =================
        float* xf    = (float*)d_ws;
        float* hbuf  = xf   + (size_t)N * Dn;
        float* qB    = hbuf + (size_t)N * Dn;
        float* attn  = qB   + (size_t)N * D3;
        float* mlp   = qB;   // overlay

        embed_kernel<<<N, 256, 0, stream>>>(idx, wte, wpe, xf);
        for (int l = 0; l < Ln; ++l) {
            ln_kernel<<<N, 256, 0, stream>>>(xf, ln1w + (size_t)l*Dn, ln1b + (size_t)l*Dn, hbuf);
            gemm_nn<<<dim3(D3/64, N/64), 256, 0, stream>>>(
                hbuf, qkvw + (size_t)l*Dn*D3, qkvb + (size_t)l*D3, nullptr, qB, Dn, D3, 0);
            attn_kernel<float><<<dim3(Tn/32, Bn*Hn), 256, 0, stream>>>(qB, attn);
            gemm_nn<<<dim3(Dn/64, N/64), 256, 0, stream>>>(
                attn, outw + (size_t)l*Dn*Dn, outb + (size_t)l*Dn, xf, xf, Dn, Dn, 0);
            ln_kernel<<<N, 256, 0, stream>>>(xf, ln2w + (size_t)l*Dn, ln2b + (size_t)l*Dn, hbuf);
            gemm_nn<<<dim3(DFFn/64, N/64), 256, 0, stream>>>(
                hbuf, fc1w + (size_t)l*Dn*DFFn, fc1b + (size_t)l*DFFn, nullptr, mlp, Dn, DFFn, 1);
            gemm_nn<<<dim3(Dn/64, N/64), 256, 0, stream>>>(
                mlp, fc2w + (size_t)l*DFFn*Dn, fc2b + (size_t)l*Dn, xf, xf, DFFn, Dn, 0);
        }
        ln_kernel<<<N, 256, 0, stream>>>(xf, lnfw, lnfb, hbuf);
        gemm_nt<<<dim3((Vn + 63)/64, N/64), 256, 0, stream>>>(hbuf, headw, logits, Dn, Vn);
    }
}

// Round 13
// 3292.349 us; speedup vs baseline: 4.6062x; 1.5536x over previous
//
#include <hip/hip_runtime.h>
#include <hip/hip_bf16.h>

// GPT-2-ish forward. bf16-MFMA GEMMs + bf16-MFMA flash attention (fp32 softmax).
// B=2 T=1024 D=1024 H=16 DH=64 L=8 DFF=4096 V=50257.
// R12 validated base: 5.11 ms, absmax 0.03125. This round: MFMA attention,
// XCD-swizzled head GEMM, 128x64 tiles for out/fc2.

constexpr int Tn  = 1024;
constexpr int Dn  = 1024;
constexpr int Hn  = 16;
constexpr int DHn = 64;
constexpr int D3  = 3072;   // 3*D
constexpr int DFFn = 4096;
constexpr int Ln  = 8;
constexpr int Bn  = 2;
constexpr int Vn  = 50257;

#define DEV_INLINE __device__ __forceinline__

typedef __bf16 bf16x8 __attribute__((ext_vector_type(8)));
typedef __bf16 bf16x4 __attribute__((ext_vector_type(4)));
typedef float  f32x4  __attribute__((ext_vector_type(4)));

DEV_INLINE float gelu_exact(float v) {
    return 0.5f * v * (1.0f + erff(v * 0.70710678118654752f));
}

// global -> LDS async 16B copy (linear LDS dest = wave-uniform base + lane*16)
typedef const __attribute__((address_space(1))) void* gas_ptr;
typedef __attribute__((address_space(3))) void*       las_ptr;
DEV_INLINE void g2lds16(const void* g, void* l) {
    __builtin_amdgcn_global_load_lds((gas_ptr)g, (las_ptr)l, 16, 0, 0);
}

// ---------------- embedding: x = wte[idx] + wpe ----------------
__global__ __launch_bounds__(256) void embed_kernel(
    const int* __restrict__ idx, const float* __restrict__ wte,
    const float* __restrict__ wpe, float* __restrict__ x)
{
    const int n   = blockIdx.x;
    const int t   = n & (Tn - 1);
    const int tok = idx[n];
    const int tid = threadIdx.x;
    float4 a = reinterpret_cast<const float4*>(wte + (size_t)tok * Dn)[tid];
    float4 p = reinterpret_cast<const float4*>(wpe + (size_t)t   * Dn)[tid];
    a.x += p.x; a.y += p.y; a.z += p.z; a.w += p.w;
    reinterpret_cast<float4*>(x + (size_t)n * Dn)[tid] = a;
}

// ---------------- layernorm fp32 -> fp32 ----------------
__global__ __launch_bounds__(256) void ln_kernel(
    const float* __restrict__ x, const float* __restrict__ w,
    const float* __restrict__ b, float* __restrict__ y)
{
    const int n   = blockIdx.x;
    const int tid = threadIdx.x;
    float4 v = reinterpret_cast<const float4*>(x + (size_t)n * Dn)[tid];
    float s  = v.x + v.y + v.z + v.w;
    float ss = v.x*v.x + v.y*v.y + v.z*v.z + v.w*v.w;
    #pragma unroll
    for (int off = 32; off > 0; off >>= 1) {
        s  += __shfl_xor(s,  off);
        ss += __shfl_xor(ss, off);
    }
    __shared__ float red[8];
    const int wid = tid >> 6;
    if ((tid & 63) == 0) { red[wid*2] = s; red[wid*2+1] = ss; }
    __syncthreads();
    const float S  = red[0] + red[2] + red[4] + red[6];
    const float SS = red[1] + red[3] + red[5] + red[7];
    const float mean = S * (1.0f / Dn);
    const float var  = SS * (1.0f / Dn) - mean * mean;
    const float inv  = rsqrtf(var + 1e-5f);
    const float4 wv = reinterpret_cast<const float4*>(w)[tid];
    const float4 bv = reinterpret_cast<const float4*>(b)[tid];
    float4 o;
    o.x = (v.x - mean) * inv * wv.x + bv.x;
    o.y = (v.y - mean) * inv * wv.y + bv.y;
    o.z = (v.z - mean) * inv * wv.z + bv.z;
    o.w = (v.w - mean) * inv * wv.w + bv.w;
    reinterpret_cast<float4*>(y + (size_t)n * Dn)[tid] = o;
}

// ---------------- layernorm fp32 -> bf16 ----------------
__global__ __launch_bounds__(256) void ln_bf16_kernel(
    const float* __restrict__ x, const float* __restrict__ w,
    const float* __restrict__ b, __bf16* __restrict__ y)
{
    const int n   = blockIdx.x;
    const int tid = threadIdx.x;
    float4 v = reinterpret_cast<const float4*>(x + (size_t)n * Dn)[tid];
    float s  = v.x + v.y + v.z + v.w;
    float ss = v.x*v.x + v.y*v.y + v.z*v.z + v.w*v.w;
    #pragma unroll
    for (int off = 32; off > 0; off >>= 1) {
        s  += __shfl_xor(s,  off);
        ss += __shfl_xor(ss, off);
    }
    __shared__ float red[8];
    const int wid = tid >> 6;
    if ((tid & 63) == 0) { red[wid*2] = s; red[wid*2+1] = ss; }
    __syncthreads();
    const float S  = red[0] + red[2] + red[4] + red[6];
    const float SS = red[1] + red[3] + red[5] + red[7];
    const float mean = S * (1.0f / Dn);
    const float var  = SS * (1.0f / Dn) - mean * mean;
    const float inv  = rsqrtf(var + 1e-5f);
    const float4 wv = reinterpret_cast<const float4*>(w)[tid];
    const float4 bv = reinterpret_cast<const float4*>(b)[tid];
    bf16x4 o;
    o[0] = (__bf16)((v.x - mean) * inv * wv.x + bv.x);
    o[1] = (__bf16)((v.y - mean) * inv * wv.y + bv.y);
    o[2] = (__bf16)((v.z - mean) * inv * wv.z + bv.z);
    o[3] = (__bf16)((v.w - mean) * inv * wv.w + bv.w);
    reinterpret_cast<bf16x4*>(y + (size_t)n * Dn)[tid] = o;
}

// ---------------- weight prep: W[K,M] fp32 -> Wt[M,K] bf16 (per layer z) ----
__global__ __launch_bounds__(256) void transpose_bf16_kernel(
    const float* __restrict__ W, __bf16* __restrict__ Wt, int K, int M)
{
    const int l  = blockIdx.z;
    const int k0 = blockIdx.y * 32, m0 = blockIdx.x * 32;
    __shared__ float t[32][33];
    const int tid = threadIdx.x;
    const int r = tid >> 3, c4 = (tid & 7) * 4;
    const float4 v = *reinterpret_cast<const float4*>(
        W + ((size_t)l * K + k0 + r) * M + m0 + c4);
    t[r][c4+0] = v.x; t[r][c4+1] = v.y; t[r][c4+2] = v.z; t[r][c4+3] = v.w;
    __syncthreads();
    bf16x4 o;
    o[0] = (__bf16)t[c4+0][r]; o[1] = (__bf16)t[c4+1][r];
    o[2] = (__bf16)t[c4+2][r]; o[3] = (__bf16)t[c4+3][r];
    *reinterpret_cast<bf16x4*>(Wt + ((size_t)l * M + m0 + r) * K + k0 + c4) = o;
}

// ---------------- fp32 -> bf16 elementwise (head weight) ----------------
__global__ __launch_bounds__(256) void cvt_bf16_kernel(
    const float* __restrict__ in, __bf16* __restrict__ out)
{
    const int i = blockIdx.x * 256 + threadIdx.x;
    float4 v = reinterpret_cast<const float4*>(in)[i];
    bf16x4 o;
    o[0] = (__bf16)v.x; o[1] = (__bf16)v.y; o[2] = (__bf16)v.z; o[3] = (__bf16)v.w;
    reinterpret_cast<bf16x4*>(out)[i] = o;
}

// ---------------- bf16 MFMA GEMM: C[N,M] = A[N,K] @ Bt[M,K]^T ----------------
// EPI: 0 = +bias -> fp32 | 1 = +bias,gelu -> bf16 | 2 = +bias+res -> fp32
//      3 = plain -> fp32, M bounds-checked (head; Bt must have >=2MB pad after)
// SWZ: 1 = 1-D grid, XCD-bijective mapping (all token-tiles of a vocab panel
//      on one XCD; grid must be 6400 = 400 panels x 16 token tiles).
// 256 threads = 4 waves (2x2); wave tile (BM/2)x(BN/2); mfma 16x16x32, BK=32.
template <int BM, int BN, int EPI, int SWZ = 0>
__global__ __launch_bounds__(256) void gemm_bf16(
    const __bf16* __restrict__ A, const __bf16* __restrict__ Bt,
    const float* __restrict__ bias, const float* res,
    void* Cout, int K, int M)
{
    constexpr int BK = 32;
    constexpr int FM = BM / 32, FN = BN / 32;   // 16x16 frags per wave
    __shared__ __bf16 As[BM * BK];
    __shared__ __bf16 Bs[BN * BK];

    const int tid  = threadIdx.x;
    const int lane = tid & 63, wid = tid >> 6;
    const int wr = wid >> 1, wc = wid & 1;

    int bx, by;
    if (SWZ) {
        const int flat = blockIdx.x;        // 0..6399
        const int s    = flat >> 3;         // 0..799 per-XCD sequence
        bx = (s >> 4) * 8 + (flat & 7);     // vocab panel 0..399 (panel%8 = XCD)
        by = s & 15;                        // token tile 0..15
    } else { bx = blockIdx.x; by = blockIdx.y; }
    const int n0 = by * BM, m0 = bx * BN;

    f32x4 acc[FM][FN] = {};

    // staging geometry: per 4KB issue, tid covers row=(i*64 + tid/4), kcol=(tid%4)*8
    const int rs = tid >> 2;
    const int kc = (tid & 3) * 8;
    const __bf16* Ab = A  + (size_t)n0 * K + kc;
    const __bf16* Bb = Bt + (size_t)m0 * K + kc;

    for (int k0 = 0; k0 < K; k0 += BK) {
        #pragma unroll
        for (int i = 0; i < (BM * BK) / 2048; ++i)
            g2lds16(Ab + (size_t)(i * 64 + rs) * K + k0,
                    (char*)As + i * 4096 + tid * 16);
        #pragma unroll
        for (int i = 0; i < (BN * BK) / 2048; ++i)
            g2lds16(Bb + (size_t)(i * 64 + rs) * K + k0,
                    (char*)Bs + i * 4096 + tid * 16);
        __syncthreads();   // drains vmcnt -> staged data visible

        const int ko = (lane >> 4) * 8;
        bf16x8 af[FM], bf[FN];
        #pragma unroll
        for (int mi = 0; mi < FM; ++mi)
            af[mi] = *reinterpret_cast<const bf16x8*>(
                &As[(wr * (BM/2) + mi * 16 + (lane & 15)) * BK + ko]);
        #pragma unroll
        for (int ni = 0; ni < FN; ++ni)
            bf[ni] = *reinterpret_cast<const bf16x8*>(
                &Bs[(wc * (BN/2) + ni * 16 + (lane & 15)) * BK + ko]);
        #pragma unroll
        for (int mi = 0; mi < FM; ++mi)
            #pragma unroll
            for (int ni = 0; ni < FN; ++ni)
                acc[mi][ni] = __builtin_amdgcn_mfma_f32_16x16x32_bf16(
                    af[mi], bf[ni], acc[mi][ni], 0, 0, 0);
        __syncthreads();   // all waves done before next stage overwrites
    }

    // epilogue: C/D mapping col=lane&15, row=(lane>>4)*4+reg  [HW-validated R12]
    const int cl = lane & 15, rg = lane >> 4;
    const int row0 = n0 + wr * (BM/2);
    const int col0 = m0 + wc * (BN/2);
    #pragma unroll
    for (int mi = 0; mi < FM; ++mi) {
        #pragma unroll
        for (int ni = 0; ni < FN; ++ni) {
            const int col = col0 + ni * 16 + cl;
            if (EPI == 3 && col >= M) continue;
            const float bv = (EPI == 3) ? 0.0f : bias[col];
            #pragma unroll
            for (int r = 0; r < 4; ++r) {
                const int row = row0 + mi * 16 + rg * 4 + r;
                float v = acc[mi][ni][r] + bv;
                if (EPI == 2) v += res[(size_t)row * M + col];
                if (EPI == 1) {
                    ((__bf16*)Cout)[(size_t)row * M + col] = (__bf16)gelu_exact(v);
                } else {
                    ((float*)Cout)[(size_t)row * M + col] = v;
                }
            }
        }
    }
}

// ---------------- bf16-MFMA causal flash attention ----------------
// grid: (T/64, B*H) = (16, 32). 256 threads = 4 waves; wave w owns q-rows
// [w*16, w*16+16). QBLK=64, KVBLK=64, DH=64. Softmax/m/l/rescale in fp32;
// only MFMA inputs (Q*scale, K, P, V) are bf16. P round-trips via LDS.
__global__ __launch_bounds__(256) void attn_mfma_kernel(
    const float* __restrict__ qkv, __bf16* __restrict__ out)
{
    const int qt  = blockIdx.x;
    const int bh  = blockIdx.y;
    const int b   = bh >> 4, h = bh & 15;
    const int tid = threadIdx.x, lane = tid & 63, w = tid >> 6;

    __shared__ __bf16 Ks[64][72];   // [kv][dh]   (stride 144B, 16B-aligned frags)
    __shared__ __bf16 Vt[64][72];   // [dh][kv]   (transposed at stage time)
    __shared__ __bf16 Ps[64][72];   // [q][kv]

    // Q fragments in registers (A-operand), pre-scaled by 1/sqrt(DH)
    bf16x8 qf[2];
    {
        const int row = qt*64 + w*16 + (lane & 15);
        const float* qp = qkv + (size_t)(b*Tn + row) * D3 + h*DHn + ((lane >> 4) * 8);
        #pragma unroll
        for (int kk = 0; kk < 2; ++kk) {
            const float4 a = *reinterpret_cast<const float4*>(qp + kk*32);
            const float4 c = *reinterpret_cast<const float4*>(qp + kk*32 + 4);
            qf[kk][0] = (__bf16)(a.x*0.125f); qf[kk][1] = (__bf16)(a.y*0.125f);
            qf[kk][2] = (__bf16)(a.z*0.125f); qf[kk][3] = (__bf16)(a.w*0.125f);
            qf[kk][4] = (__bf16)(c.x*0.125f); qf[kk][5] = (__bf16)(c.y*0.125f);
            qf[kk][6] = (__bf16)(c.z*0.125f); qf[kk][7] = (__bf16)(c.w*0.125f);
        }
    }

    f32x4 o[4] = {};                 // O accumulator, 4 dh-frags
    float m_i[4], l_i[4];
    #pragma unroll
    for (int r = 0; r < 4; ++r) { m_i[r] = -1e30f; l_i[r] = 0.f; }

    const int sr = tid >> 2;          // stage row 0..63
    const int sc = (tid & 3) * 16;    // stage col base {0,16,32,48}

    for (int kvt = 0; kvt <= qt; ++kvt) {
        __syncthreads();   // prev tile's Ks/Vt/Ps fully consumed
        const size_t base = (size_t)(b*Tn + kvt*64 + sr) * D3 + h*DHn + sc;
        // K tile -> Ks[kv][dh], vectorized
        {
            bf16x8 k8[2];
            #pragma unroll
            for (int i = 0; i < 2; ++i) {
                const float4 a = *reinterpret_cast<const float4*>(qkv + base + Dn + i*8);
                const float4 c = *reinterpret_cast<const float4*>(qkv + base + Dn + i*8 + 4);
                k8[i][0]=(__bf16)a.x; k8[i][1]=(__bf16)a.y; k8[i][2]=(__bf16)a.z; k8[i][3]=(__bf16)a.w;
                k8[i][4]=(__bf16)c.x; k8[i][5]=(__bf16)c.y; k8[i][6]=(__bf16)c.z; k8[i][7]=(__bf16)c.w;
            }
            *reinterpret_cast<bf16x8*>(&Ks[sr][sc])     = k8[0];
            *reinterpret_cast<bf16x8*>(&Ks[sr][sc + 8]) = k8[1];
        }
        // V tile -> Vt[dh][kv], scalar transposed stores (predicted conflict spot)
        #pragma unroll
        for (int i = 0; i < 4; ++i) {
            const float4 v4 = *reinterpret_cast<const float4*>(qkv + base + 2*Dn + i*4);
            Vt[sc + i*4 + 0][sr] = (__bf16)v4.x;
            Vt[sc + i*4 + 1][sr] = (__bf16)v4.y;
            Vt[sc + i*4 + 2][sr] = (__bf16)v4.z;
            Vt[sc + i*4 + 3][sr] = (__bf16)v4.w;
        }
        __syncthreads();   // staged data visible

        // S = Q K^T  (wave strip: 16 q-rows x 64 kv)
        f32x4 s4[4] = {};
        #pragma unroll
        for (int kk = 0; kk < 2; ++kk) {
            const int ko = kk*32 + (lane >> 4) * 8;
            #pragma unroll
            for (int fn = 0; fn < 4; ++fn) {
                const bf16x8 kf = *reinterpret_cast<const bf16x8*>(
                    &Ks[fn*16 + (lane & 15)][ko]);
                s4[fn] = __builtin_amdgcn_mfma_f32_16x16x32_bf16(qf[kk], kf, s4[fn], 0, 0, 0);
            }
        }
        // causal mask (diagonal tile only): kv_local > q_local -> -inf
        if (kvt == qt) {
            const int ql = w*16 + (lane >> 4) * 4;
            #pragma unroll
            for (int fn = 0; fn < 4; ++fn) {
                const int kl = fn*16 + (lane & 15);
                #pragma unroll
                for (int r = 0; r < 4; ++r)
                    if (kl > ql + r) s4[fn][r] = -1e30f;
            }
        }
        // online softmax per row (fp32); row r owned by 16 lanes sharing lane>>4
        float p[4][4];   // [fn][r]
        #pragma unroll
        for (int r = 0; r < 4; ++r) {
            float tmax = fmaxf(fmaxf(s4[0][r], s4[1][r]), fmaxf(s4[2][r], s4[3][r]));
            tmax = fmaxf(tmax, __shfl_xor(tmax, 1));
            tmax = fmaxf(tmax, __shfl_xor(tmax, 2));
            tmax = fmaxf(tmax, __shfl_xor(tmax, 4));
            tmax = fmaxf(tmax, __shfl_xor(tmax, 8));
            const float mn   = fmaxf(m_i[r], tmax);
            const float corr = expf(m_i[r] - mn);
            float ps = 0.f;
            #pragma unroll
            for (int fn = 0; fn < 4; ++fn) { p[fn][r] = expf(s4[fn][r] - mn); ps += p[fn][r]; }
            ps += __shfl_xor(ps, 1); ps += __shfl_xor(ps, 2);
            ps += __shfl_xor(ps, 4); ps += __shfl_xor(ps, 8);
            l_i[r] = l_i[r] * corr + ps;
            m_i[r] = mn;
            #pragma unroll
            for (int ofn = 0; ofn < 4; ++ofn) o[ofn][r] *= corr;
        }
        // P -> LDS (bf16), C/D layout -> A layout round-trip
        {
            const int prow = w*16 + (lane >> 4) * 4;
            #pragma unroll
            for (int fn = 0; fn < 4; ++fn)
                #pragma unroll
                for (int r = 0; r < 4; ++r)
                    Ps[prow + r][fn*16 + (lane & 15)] = (__bf16)p[fn][r];
        }
        __syncthreads();   // Ps visible to all lanes

        // O += P V   (A = Ps rows=q, Bt = Vt rows=dh)
        #pragma unroll
        for (int kk = 0; kk < 2; ++kk) {
            const int ko = kk*32 + (lane >> 4) * 8;
            const bf16x8 pa = *reinterpret_cast<const bf16x8*>(
                &Ps[w*16 + (lane & 15)][ko]);
            #pragma unroll
            for (int ofn = 0; ofn < 4; ++ofn) {
                const bf16x8 vf = *reinterpret_cast<const bf16x8*>(
                    &Vt[ofn*16 + (lane & 15)][ko]);
                o[ofn] = __builtin_amdgcn_mfma_f32_16x16x32_bf16(pa, vf, o[ofn], 0, 0, 0);
            }
        }
    }

    // epilogue: out[token][h*64+dh] = O/l  (bf16)
    const int orow = qt*64 + w*16 + (lane >> 4) * 4;
    #pragma unroll
    for (int ofn = 0; ofn < 4; ++ofn)
        #pragma unroll
        for (int r = 0; r < 4; ++r)
            out[(size_t)(b*Tn + orow + r) * Dn + h*DHn + ofn*16 + (lane & 15)]
                = (__bf16)(o[ofn][r] / l_i[r]);
}

// ---------------- fp32 GEMM NN (fallback path) ----------------
__global__ __launch_bounds__(256) void gemm_nn(
    const float* __restrict__ A, const float* __restrict__ W,
    const float* __restrict__ bias, const float* res,
    float* C, int K, int M, int act)
{
    const int m0  = blockIdx.x * 64;
    const int n0  = blockIdx.y * 64;
    const int tid = threadIdx.x;

    __shared__ float As[64][17];
    alignas(16) __shared__ float Ws[16][68];

    const int ar = tid >> 4, ac = tid & 15;
    const int wr = tid >> 6, wc = tid & 63;
    const int tx = tid & 15, ty = tid >> 4;

    float acc[4][4] = {};

    for (int k0 = 0; k0 < K; k0 += 16) {
        #pragma unroll
        for (int i = 0; i < 4; ++i)
            As[ar + i*16][ac] = A[(size_t)(n0 + ar + i*16) * K + k0 + ac];
        #pragma unroll
        for (int i = 0; i < 4; ++i)
            Ws[wr + i*4][wc] = W[(size_t)(k0 + wr + i*4) * M + m0 + wc];
        __syncthreads();
        #pragma unroll
        for (int k = 0; k < 16; ++k) {
            const float a0 = As[tx*4+0][k];
            const float a1 = As[tx*4+1][k];
            const float a2 = As[tx*4+2][k];
            const float a3 = As[tx*4+3][k];
            const float4 bq = *reinterpret_cast<const float4*>(&Ws[k][ty*4]);
            acc[0][0] += a0*bq.x; acc[0][1] += a0*bq.y; acc[0][2] += a0*bq.z; acc[0][3] += a0*bq.w;
            acc[1][0] += a1*bq.x; acc[1][1] += a1*bq.y; acc[1][2] += a1*bq.z; acc[1][3] += a1*bq.w;
            acc[2][0] += a2*bq.x; acc[2][1] += a2*bq.y; acc[2][2] += a2*bq.z; acc[2][3] += a2*bq.w;
            acc[3][0] += a3*bq.x; acc[3][1] += a3*bq.y; acc[3][2] += a3*bq.z; acc[3][3] += a3*bq.w;
        }
        __syncthreads();
    }

    float4 bv = make_float4(0.f, 0.f, 0.f, 0.f);
    if (bias) bv = *reinterpret_cast<const float4*>(&bias[m0 + ty*4]);
    #pragma unroll
    for (int i = 0; i < 4; ++i) {
        const size_t row = (size_t)(n0 + tx*4 + i);
        float4 v = make_float4(acc[i][0] + bv.x, acc[i][1] + bv.y,
                               acc[i][2] + bv.z, acc[i][3] + bv.w);
        if (res) {
            const float4 r4 = *reinterpret_cast<const float4*>(&res[row * M + m0 + ty*4]);
            v.x += r4.x; v.y += r4.y; v.z += r4.z; v.w += r4.w;
        }
        if (act == 1) {
            v.x = gelu_exact(v.x); v.y = gelu_exact(v.y);
            v.z = gelu_exact(v.z); v.w = gelu_exact(v.w);
        }
        *reinterpret_cast<float4*>(&C[row * M + m0 + ty*4]) = v;
    }
}

// ---------------- fp32 GEMM NT (fallback head) ----------------
__global__ __launch_bounds__(256) void gemm_nt(
    const float* __restrict__ A, const float* __restrict__ Bt,
    float* __restrict__ C, int K, int M)
{
    const int m0  = blockIdx.x * 64;
    const int n0  = blockIdx.y * 64;
    const int tid = threadIdx.x;

    __shared__ float As[64][17];
    alignas(16) __shared__ float Bs[16][68];

    const int ar = tid >> 4, ac = tid & 15;
    const int bk = tid & 15, bm = tid >> 4;
    const int tx = tid & 15, ty = tid >> 4;

    float acc[4][4] = {};

    for (int k0 = 0; k0 < K; k0 += 16) {
        #pragma unroll
        for (int i = 0; i < 4; ++i)
            As[ar + i*16][ac] = A[(size_t)(n0 + ar + i*16) * K + k0 + ac];
        #pragma unroll
        for (int i = 0; i < 4; ++i) {
            const int m = bm + i*16;
            Bs[bk][m] = (m0 + m < M) ? Bt[(size_t)(m0 + m) * K + k0 + bk] : 0.f;
        }
        __syncthreads();
        #pragma unroll
        for (int k = 0; k < 16; ++k) {
            const float a0 = As[tx*4+0][k];
            const float a1 = As[tx*4+1][k];
            const float a2 = As[tx*4+2][k];
            const float a3 = As[tx*4+3][k];
            const float4 bq = *reinterpret_cast<const float4*>(&Bs[k][ty*4]);
            acc[0][0] += a0*bq.x; acc[0][1] += a0*bq.y; acc[0][2] += a0*bq.z; acc[0][3] += a0*bq.w;
            acc[1][0] += a1*bq.x; acc[1][1] += a1*bq.y; acc[1][2] += a1*bq.z; acc[1][3] += a1*bq.w;
            acc[2][0] += a2*bq.x; acc[2][1] += a2*bq.y; acc[2][2] += a2*bq.z; acc[2][3] += a2*bq.w;
            acc[3][0] += a3*bq.x; acc[3][1] += a3*bq.y; acc[3][2] += a3*bq.z; acc[3][3] += a3*bq.w;
        }
        __syncthreads();
    }

    #pragma unroll
    for (int i = 0; i < 4; ++i) {
        const size_t row = (size_t)(n0 + tx*4 + i);
        #pragma unroll
        for (int j = 0; j < 4; ++j) {
            const int m = m0 + ty*4 + j;
            if (m < M) C[row * M + m] = acc[i][j];
        }
    }
}

// ---------------- fp32 flash attention (fallback path) ----------------
template <typename OT>
__global__ __launch_bounds__(256) void attn_kernel(
    const float* __restrict__ qkv, OT* __restrict__ out)
{
    const int qt   = blockIdx.x;
    const int bh   = blockIdx.y;
    const int b    = bh >> 4;
    const int h    = bh & 15;
    const int tid  = threadIdx.x;
    const int lane = tid & 63;
    const int w    = tid >> 6;

    __shared__ float Qs[32][65];
    __shared__ float Ks[64][65];
    __shared__ float Vs[64][65];
    __shared__ float Psh[32][64];

    const float scale = 0.125f;

    #pragma unroll
    for (int i = 0; i < 2; ++i) {
        const int f = tid + i*256;
        const int r = f >> 4, c = (f & 15) * 4;
        const float4 q = *reinterpret_cast<const float4*>(
            qkv + (size_t)(b*Tn + qt*32 + r) * D3 + h*DHn + c);
        Qs[r][c+0] = q.x * scale; Qs[r][c+1] = q.y * scale;
        Qs[r][c+2] = q.z * scale; Qs[r][c+3] = q.w * scale;
    }

    float m_i[8], l_i[8], o_i[8];
    #pragma unroll
    for (int i = 0; i < 8; ++i) { m_i[i] = -1e30f; l_i[i] = 0.f; o_i[i] = 0.f; }

    const int ktmax = (qt*32 + 31) >> 6;
    for (int kt = 0; kt <= ktmax; ++kt) {
        __syncthreads();
        #pragma unroll
        for (int i = 0; i < 4; ++i) {
            const int f = tid + i*256;
            const int r = f >> 4, c = (f & 15) * 4;
            const size_t base = (size_t)(b*Tn + kt*64 + r) * D3 + h*DHn + c;
            const float4 kq = *reinterpret_cast<const float4*>(qkv + base + Dn);
            const float4 vq = *reinterpret_cast<const float4*>(qkv + base + 2*Dn);
            Ks[r][c+0]=kq.x; Ks[r][c+1]=kq.y; Ks[r][c+2]=kq.z; Ks[r][c+3]=kq.w;
            Vs[r][c+0]=vq.x; Vs[r][c+1]=vq.y; Vs[r][c+2]=vq.z; Vs[r][c+3]=vq.w;
        }
        __syncthreads();

        float s[8];
        #pragma unroll
        for (int i = 0; i < 8; ++i) s[i] = 0.f;
        for (int d = 0; d < 64; ++d) {
            const float kv = Ks[lane][d];
            #pragma unroll
            for (int i = 0; i < 8; ++i) s[i] += Qs[w*8+i][d] * kv;
        }
        const int kg = kt*64 + lane;
        #pragma unroll
        for (int i = 0; i < 8; ++i) {
            const int qg = qt*32 + w*8 + i;
            if (kg > qg) s[i] = -1e30f;
        }

        #pragma unroll
        for (int i = 0; i < 8; ++i) {
            float tmax = s[i];
            #pragma unroll
            for (int off = 32; off > 0; off >>= 1)
                tmax = fmaxf(tmax, __shfl_xor(tmax, off));
            const float mn   = fmaxf(m_i[i], tmax);
            const float p    = expf(s[i] - mn);
            const float corr = expf(m_i[i] - mn);
            float psum = p;
            #pragma unroll
            for (int off = 32; off > 0; off >>= 1)
                psum += __shfl_xor(psum, off);
            l_i[i] = l_i[i] * corr + psum;
            m_i[i] = mn;
            o_i[i] *= corr;
            Psh[w*8+i][lane] = p;
        }
        __syncthreads();

        for (int kc = 0; kc < 64; ++kc) {
            const float vv = Vs[kc][lane];
            #pragma unroll
            for (int i = 0; i < 8; ++i) o_i[i] += Psh[w*8+i][kc] * vv;
        }
    }

    #pragma unroll
    for (int i = 0; i < 8; ++i) {
        const int r = qt*32 + w*8 + i;
        out[(size_t)(b*Tn + r) * Dn + h*DHn + lane] = (OT)(o_i[i] / l_i[i]);
    }
}

// ---------------- launch ----------------
extern "C" void kernel_launch(void* const* d_in, const int* in_sizes, int n_in,
                              void* d_out, int out_size, void* d_ws, size_t ws_size,
                              hipStream_t stream) {
    (void)in_sizes; (void)n_in; (void)out_size;

    const int* idx     = (const int*)  d_in[0];
    const float* wte   = (const float*)d_in[1];
    const float* wpe   = (const float*)d_in[2];
    const float* ln1w  = (const float*)d_in[3];
    const float* ln1b  = (const float*)d_in[4];
    const float* qkvw  = (const float*)d_in[5];
    const float* qkvb  = (const float*)d_in[6];
    const float* outw  = (const float*)d_in[7];
    const float* outb  = (const float*)d_in[8];
    const float* ln2w  = (const float*)d_in[9];
    const float* ln2b  = (const float*)d_in[10];
    const float* fc1w  = (const float*)d_in[11];
    const float* fc1b  = (const float*)d_in[12];
    const float* fc2w  = (const float*)d_in[13];
    const float* fc2b  = (const float*)d_in[14];
    const float* lnfw  = (const float*)d_in[15];
    const float* lnfb  = (const float*)d_in[16];
    const float* headw = (const float*)d_in[17];

    const int N = Bn * Tn;   // 2048
    float* logits = (float*)d_out;

    // ---- bf16-path workspace layout (bytes) ----
    char* p = (char*)d_ws;
    size_t off = 0;
    auto take = [&](size_t bytes) { char* r = p + off; off += bytes; return r; };
    float*  x      = (float*) take((size_t)N * Dn * 4);
    __bf16* hbufb  = (__bf16*)take((size_t)N * Dn * 2);
    float*  qkvB   = (float*) take((size_t)N * D3 * 4);      // mlpb aliases this
    __bf16* attnb  = (__bf16*)take((size_t)N * Dn * 2);
    __bf16* qkvw_t = (__bf16*)take((size_t)Ln * Dn * D3 * 2);
    __bf16* outw_t = (__bf16*)take((size_t)Ln * Dn * Dn * 2);
    __bf16* fc1w_t = (__bf16*)take((size_t)Ln * Dn * DFFn * 2);
    __bf16* fc2w_t = (__bf16*)take((size_t)Ln * DFFn * Dn * 2);
    __bf16* headb  = (__bf16*)take((size_t)Vn * Dn * 2);
    off += (size_t)2 << 20;                                  // 2MB pad: head OOB staging
    __bf16* mlpb   = (__bf16*)qkvB;                          // overlay (disjoint liveness)

    if (ws_size >= off) {
        // ================= bf16 MFMA path =================
        embed_kernel<<<N, 256, 0, stream>>>(idx, wte, wpe, x);

        transpose_bf16_kernel<<<dim3(D3/32,  Dn/32,  Ln), 256, 0, stream>>>(qkvw, qkvw_t, Dn, D3);
        transpose_bf16_kernel<<<dim3(Dn/32,  Dn/32,  Ln), 256, 0, stream>>>(outw, outw_t, Dn, Dn);
        transpose_bf16_kernel<<<dim3(DFFn/32, Dn/32, Ln), 256, 0, stream>>>(fc1w, fc1w_t, Dn, DFFn);
        transpose_bf16_kernel<<<dim3(Dn/32, DFFn/32, Ln), 256, 0, stream>>>(fc2w, fc2w_t, DFFn, Dn);
        cvt_bf16_kernel<<<Vn, 256, 0, stream>>>(headw, headb);   // V*D/4 = 256*Vn exactly

        for (int l = 0; l < Ln; ++l) {
            ln_bf16_kernel<<<N, 256, 0, stream>>>(x, ln1w + (size_t)l*Dn, ln1b + (size_t)l*Dn, hbufb);
            gemm_bf16<128,128,0><<<dim3(D3/128, N/128), 256, 0, stream>>>(
                hbufb, qkvw_t + (size_t)l*Dn*D3, qkvb + (size_t)l*D3, nullptr, qkvB, Dn, D3);
            attn_mfma_kernel<<<dim3(Tn/64, Bn*Hn), 256, 0, stream>>>(qkvB, attnb);
            gemm_bf16<128,64,2><<<dim3(Dn/64, N/128), 256, 0, stream>>>(
                attnb, outw_t + (size_t)l*Dn*Dn, outb + (size_t)l*Dn, x, x, Dn, Dn);
            ln_bf16_kernel<<<N, 256, 0, stream>>>(x, ln2w + (size_t)l*Dn, ln2b + (size_t)l*Dn, hbufb);
            gemm_bf16<128,128,1><<<dim3(DFFn/128, N/128), 256, 0, stream>>>(
                hbufb, fc1w_t + (size_t)l*Dn*DFFn, fc1b + (size_t)l*DFFn, nullptr, mlpb, Dn, DFFn);
            gemm_bf16<128,64,2><<<dim3(Dn/64, N/128), 256, 0, stream>>>(
                mlpb, fc2w_t + (size_t)l*DFFn*Dn, fc2b + (size_t)l*Dn, x, x, DFFn, Dn);
        }

        ln_bf16_kernel<<<N, 256, 0, stream>>>(x, lnfw, lnfb, hbufb);
        // head: XCD-bijective swizzle, 400 panels x 16 token tiles (panels >=393
        // read only the 2MB ws pad and write nothing)
        gemm_bf16<128,128,3,1><<<dim3(400*16), 256, 0, stream>>>(
            hbufb, headb, nullptr, nullptr, logits, Dn, Vn);
    } else {
        // ================= fp32 fallback (validated baseline) =================
        float* xf    = (float*)d_ws;
        float* hbuf  = xf   + (size_t)N * Dn;
        float* qB    = hbuf + (size_t)N * Dn;
        float* attn  = qB   + (size_t)N * D3;
        float* mlp   = qB;   // overlay

        embed_kernel<<<N, 256, 0, stream>>>(idx, wte, wpe, xf);
        for (int l = 0; l < Ln; ++l) {
            ln_kernel<<<N, 256, 0, stream>>>(xf, ln1w + (size_t)l*Dn, ln1b + (size_t)l*Dn, hbuf);
            gemm_nn<<<dim3(D3/64, N/64), 256, 0, stream>>>(
                hbuf, qkvw + (size_t)l*Dn*D3, qkvb + (size_t)l*D3, nullptr, qB, Dn, D3, 0);
            attn_kernel<float><<<dim3(Tn/32, Bn*Hn), 256, 0, stream>>>(qB, attn);
            gemm_nn<<<dim3(Dn/64, N/64), 256, 0, stream>>>(
                attn, outw + (size_t)l*Dn*Dn, outb + (size_t)l*Dn, xf, xf, Dn, Dn, 0);
            ln_kernel<<<N, 256, 0, stream>>>(xf, ln2w + (size_t)l*Dn, ln2b + (size_t)l*Dn, hbuf);
            gemm_nn<<<dim3(DFFn/64, N/64), 256, 0, stream>>>(
                hbuf, fc1w + (size_t)l*Dn*DFFn, fc1b + (size_t)l*DFFn, nullptr, mlp, Dn, DFFn, 1);
            gemm_nn<<<dim3(Dn/64, N/64), 256, 0, stream>>>(
                mlp, fc2w + (size_t)l*DFFn*Dn, fc2b + (size_t)l*Dn, xf, xf, DFFn, Dn, 0);
        }
        ln_kernel<<<N, 256, 0, stream>>>(xf, lnfw, lnfb, hbuf);
        gemm_nt<<<dim3((Vn + 63)/64, N/64), 256, 0, stream>>>(hbuf, headw, logits, Dn, Vn);
    }
}